// Round 8
// baseline (277.315 us; speedup 1.0000x reference)
//
#include <hip/hip_runtime.h>

typedef unsigned short u16;
typedef unsigned int u32;
typedef __attribute__((ext_vector_type(8))) short bfrag;  // 8 bf16 (4 VGPRs)
typedef __attribute__((ext_vector_type(4))) short sfrag;  // 4 bf16 (2 VGPRs)
typedef __attribute__((ext_vector_type(4))) float ffrag;  // 4 fp32

// B=256, L=200, D=256, H=16, Dh=16, M=51200
// Head-major slice: [B,H,L,16], slice stride 3200 u16, b-stride 51200 u16.

__device__ __forceinline__ float bf2f(u16 u) {
    union { float f; u32 i; } c; c.i = ((u32)u) << 16; return c.f;
}
__device__ __forceinline__ u16 f2bf(float f) {           // RNE
    union { float f; u32 i; } c; c.f = f;
    u32 r = c.i + 0x7FFFu + ((c.i >> 16) & 1u);
    return (u16)(r >> 16);
}
__device__ __forceinline__ u32 pack2bf(float lo, float hi) {  // RNE pair
    union { float f; u32 i; } a, b; a.f = lo; b.f = hi;
    u32 ra = a.i + 0x7FFFu + ((a.i >> 16) & 1u);
    u32 rb = b.i + 0x7FFFu + ((b.i >> 16) & 1u);
    return (ra >> 16) | (rb & 0xFFFF0000u);
}
__device__ __forceinline__ ffrag mfma16(bfrag a, bfrag b, ffrag c) {
    return __builtin_amdgcn_mfma_f32_16x16x32_bf16(a, b, c, 0, 0, 0);
}
__device__ __forceinline__ ffrag mfma16k16(sfrag a, sfrag b, ffrag c) {
    return __builtin_amdgcn_mfma_f32_16x16x16bf16_1k(a, b, c, 0, 0, 0);
}
__device__ __forceinline__ void gload_lds16(const u16* g, u16* l) {
    __builtin_amdgcn_global_load_lds(
        (const __attribute__((address_space(1))) void*)g,
        (__attribute__((address_space(3))) void*)l, 16, 0, 0);
}

// ---------------------------------------------------------------------------
// X f32 -> bf16 (RNE). 1600 blocks x 256 thr x 32 elems = 13,107,200.
// ---------------------------------------------------------------------------
__global__ __launch_bounds__(256) void xcast_k(
    const float* __restrict__ X, u16* __restrict__ Xb)
{
    size_t base = ((size_t)blockIdx.x * 256 + threadIdx.x) * 32;
#pragma unroll
    for (int j = 0; j < 32; j += 8) {
        float4 f0 = *(const float4*)(X + base + j);
        float4 f1 = *(const float4*)(X + base + j + 4);
        uint4 v = { pack2bf(f0.x, f0.y), pack2bf(f0.z, f0.w),
                    pack2bf(f1.x, f1.y), pack2bf(f1.z, f1.w) };
        *(uint4*)(Xb + base + j) = v;
    }
}

// ---------------------------------------------------------------------------
// LDS-tiled transpose+cast: W[k][n] f32 -> Wt[n][k] bf16, 4 matrices.
// ---------------------------------------------------------------------------
__global__ __launch_bounds__(256) void wtrans_k(
    const float* __restrict__ W0, const float* __restrict__ W1,
    const float* __restrict__ W2, const float* __restrict__ W3,
    u16* __restrict__ Wt)
{
    __shared__ u16 t_s[64][72];
    const int mat = blockIdx.z;
    const float* W = (mat == 0) ? W0 : (mat == 1) ? W1 : (mat == 2) ? W2 : W3;
    const int k0 = blockIdx.x * 64, n0 = blockIdx.y * 64;
    const int r = threadIdx.x >> 2, cq = threadIdx.x & 3;

    const float* src = W + (size_t)(k0 + r) * 256 + n0 + cq * 16;
#pragma unroll
    for (int j = 0; j < 16; j += 4) {
        float4 f = *(const float4*)(src + j);
        t_s[cq * 16 + j + 0][r] = f2bf(f.x);
        t_s[cq * 16 + j + 1][r] = f2bf(f.y);
        t_s[cq * 16 + j + 2][r] = f2bf(f.z);
        t_s[cq * 16 + j + 3][r] = f2bf(f.w);
    }
    __syncthreads();
    u16* dst = Wt + ((size_t)mat * 256 + n0 + r) * 256 + k0 + cq * 16;
    *(bfrag*)(dst)     = *(const bfrag*)&t_s[r][cq * 16];
    *(bfrag*)(dst + 8) = *(const bfrag*)&t_s[r][cq * 16 + 8];
}

// ---------------------------------------------------------------------------
// bf16 GEMM via global_load_lds staging. BK=64, block tile 128x128.
// Slot j (0..1023/plane-set): plane sc=j>>7, LDS row idx=j&127 holds global
// row (idx ^ (sc<<2)) — lane-contiguous store order (DMA needs base+lane*16),
// fragment reads identical to r7's conflict-free pattern.
// QKV=true : A = Xb (bf16 l-major), grid (400,6), writes Q/K/V head-major.
// QKV=false: A = ctx (bf16 head-major), grid (400,2), writes l-major.
// ---------------------------------------------------------------------------
template<bool QKV>
__global__ __launch_bounds__(256) void gemm8_k(
    const u16* __restrict__ A, const u16* __restrict__ Wtp,
    const float* __restrict__ b0, const float* __restrict__ b1,
    const float* __restrict__ b2,
    u16* __restrict__ o0, u16* __restrict__ o1, u16* __restrict__ o2)
{
    const int m0 = blockIdx.x * 128;
    const int n0g = blockIdx.y * 128;
    const int tid = threadIdx.x;
    const int wave = tid >> 6, lane = tid & 63;
    const int quad = lane >> 4, l16 = lane & 15;
    const int wm = wave >> 1, wn = wave & 1;

    __shared__ __align__(16) u16 a_s[8][128][8];   // 16 KB
    __shared__ __align__(16) u16 b_s[8][128][8];   // 16 KB

    ffrag zf = {0.f, 0.f, 0.f, 0.f};
    ffrag acc[4][4];
#pragma unroll
    for (int mi = 0; mi < 4; mi++)
#pragma unroll
        for (int ni = 0; ni < 4; ni++) acc[mi][ni] = zf;

    // per-issue pointers (slot j = ii*256 + tid)
    const u16* aptr[4];
    const u16* bptr[4];
    u16* alds[4];
    u16* blds[4];
#pragma unroll
    for (int ii = 0; ii < 4; ii++) {
        int j   = ii * 256 + tid;
        int sc  = j >> 7;
        int row = (j & 127) ^ (sc << 2);
        if constexpr (QKV) {
            aptr[ii] = A + (size_t)(m0 + row) * 256 + sc * 8;
        } else {
            int gr = m0 + row;                       // global ctx row
            unsigned bb = (unsigned)gr / 200u, ll = gr - bb * 200u;
            int c = sc * 8;                          // k-channel at kk=0
            aptr[ii] = A + (size_t)bb * 51200 + ll * 16 + (c >> 4) * 3200 + (c & 8);
        }
        bptr[ii] = Wtp + (size_t)(n0g + row) * 256 + sc * 8;
        // wave-uniform LDS base + lane*16 (DMA deposit order)
        alds[ii] = &a_s[0][0][0] + (size_t)(ii * 256 + wave * 64) * 8;
        blds[ii] = &b_s[0][0][0] + (size_t)(ii * 256 + wave * 64) * 8;
    }

    for (int kk = 0; kk < 256; kk += 64) {
        __syncthreads();
#pragma unroll
        for (int ii = 0; ii < 4; ii++) {
            if constexpr (QKV) gload_lds16(aptr[ii] + kk, alds[ii]);
            else               gload_lds16(aptr[ii] + kk * 200, alds[ii]);  // (kk>>4)*3200
            gload_lds16(bptr[ii] + kk, blds[ii]);
        }
        __syncthreads();
#pragma unroll
        for (int ks = 0; ks < 2; ks++) {
            const int p = ks * 4 + quad;
            bfrag af[4], bf[4];
#pragma unroll
            for (int mi = 0; mi < 4; mi++) {
                int m = wm * 64 + mi * 16 + l16;
                af[mi] = *(const bfrag*)&a_s[p][m ^ (p << 2)][0];
            }
#pragma unroll
            for (int ni = 0; ni < 4; ni++) {
                int n = wn * 64 + ni * 16 + l16;
                bf[ni] = *(const bfrag*)&b_s[p][n ^ (p << 2)][0];
            }
#pragma unroll
            for (int mi = 0; mi < 4; mi++)
#pragma unroll
                for (int ni = 0; ni < 4; ni++)
                    acc[mi][ni] = mfma16(af[mi], bf[ni], acc[mi][ni]);
        }
    }

    if constexpr (QKV) {
        const float* bias = (blockIdx.y < 2) ? b0 : (blockIdx.y < 4) ? b1 : b2;
        u16* dst = (blockIdx.y < 2) ? o0 : (blockIdx.y < 4) ? o1 : o2;
#pragma unroll
        for (int ni = 0; ni < 4; ni++) {
            int nloc = (blockIdx.y & 1) * 128 + wn * 64 + ni * 16 + l16;
            float bb = bias[nloc];
            size_t hbase = (size_t)(nloc >> 4) * 3200 + (nloc & 15);
#pragma unroll
            for (int mi = 0; mi < 4; mi++) {
                int rowb = m0 + wm * 64 + mi * 16 + quad * 4;
#pragma unroll
                for (int r = 0; r < 4; r++) {
                    unsigned row = rowb + r;
                    unsigned bb_ = row / 200u, ll = row - bb_ * 200u;
                    dst[(size_t)bb_ * 51200 + hbase + ll * 16] = f2bf(acc[mi][ni][r] + bb);
                }
            }
        }
    } else {
#pragma unroll
        for (int ni = 0; ni < 4; ni++) {
            int col = n0g + wn * 64 + ni * 16 + l16;
            float bb = b0[col];
#pragma unroll
            for (int mi = 0; mi < 4; mi++) {
                int rowb = m0 + wm * 64 + mi * 16 + quad * 4;
#pragma unroll
                for (int r = 0; r < 4; r++)
                    o0[(size_t)(rowb + r) * 256 + col] = f2bf(acc[mi][ni][r] + bb);
            }
        }
    }
}

// ---------------------------------------------------------------------------
// Fallback QKV GEMM (small ws): f32 A staged+cast in-register (r7 style, RNE).
// ---------------------------------------------------------------------------
__global__ __launch_bounds__(256) void gemm_qkvf32_k(
    const float* __restrict__ Af, const u16* __restrict__ Wtp,
    const float* __restrict__ b0, const float* __restrict__ b1,
    const float* __restrict__ b2,
    u16* __restrict__ o0, u16* __restrict__ o1, u16* __restrict__ o2)
{
    const int m0 = blockIdx.x * 128;
    const int n0g = blockIdx.y * 128;
    const int tid = threadIdx.x;
    const int wave = tid >> 6, lane = tid & 63;
    const int quad = lane >> 4, l16 = lane & 15;
    const int wm = wave >> 1, wn = wave & 1;

    __shared__ __align__(16) u16 a_s[4][128][8];
    __shared__ __align__(16) u16 b_s[4][128][8];

    ffrag zf = {0.f, 0.f, 0.f, 0.f};
    ffrag acc[4][4];
#pragma unroll
    for (int mi = 0; mi < 4; mi++)
#pragma unroll
        for (int ni = 0; ni < 4; ni++) acc[mi][ni] = zf;

    const int sr = tid >> 2;
    const int sc = tid & 3;
    const u16* Wp = Wtp + (size_t)(n0g + sr) * 256 + sc * 8;
    int r0 = m0 + sr, r1 = r0 + 64;

    for (int kk = 0; kk < 256; kk += 32) {
        __syncthreads();
        const float* p0 = Af + (size_t)r0 * 256 + sc * 8 + kk;
        const float* p1 = Af + (size_t)r1 * 256 + sc * 8 + kk;
        float4 f0 = *(const float4*)p0, f1 = *(const float4*)(p0 + 4);
        float4 g0 = *(const float4*)p1, g1 = *(const float4*)(p1 + 4);
        uint4 va = { pack2bf(f0.x, f0.y), pack2bf(f0.z, f0.w),
                     pack2bf(f1.x, f1.y), pack2bf(f1.z, f1.w) };
        uint4 vb = { pack2bf(g0.x, g0.y), pack2bf(g0.z, g0.w),
                     pack2bf(g1.x, g1.y), pack2bf(g1.z, g1.w) };
        *(uint4*)&a_s[sc][sr        ^ (sc << 2)][0] = va;
        *(uint4*)&a_s[sc][(sr + 64) ^ (sc << 2)][0] = vb;
        *(bfrag*)&b_s[sc][sr        ^ (sc << 2)][0] = *(const bfrag*)(Wp + kk);
        *(bfrag*)&b_s[sc][(sr + 64) ^ (sc << 2)][0] = *(const bfrag*)(Wp + (size_t)64 * 256 + kk);
        __syncthreads();

        bfrag af[4], bfr[4];
#pragma unroll
        for (int mi = 0; mi < 4; mi++) {
            int m = wm * 64 + mi * 16 + l16;
            af[mi] = *(const bfrag*)&a_s[quad][m ^ (quad << 2)][0];
        }
#pragma unroll
        for (int ni = 0; ni < 4; ni++) {
            int n = wn * 64 + ni * 16 + l16;
            bfr[ni] = *(const bfrag*)&b_s[quad][n ^ (quad << 2)][0];
        }
#pragma unroll
        for (int mi = 0; mi < 4; mi++)
#pragma unroll
            for (int ni = 0; ni < 4; ni++)
                acc[mi][ni] = mfma16(af[mi], bfr[ni], acc[mi][ni]);
    }

    const float* bias = (blockIdx.y < 2) ? b0 : (blockIdx.y < 4) ? b1 : b2;
    u16* dst = (blockIdx.y < 2) ? o0 : (blockIdx.y < 4) ? o1 : o2;
#pragma unroll
    for (int ni = 0; ni < 4; ni++) {
        int nloc = (blockIdx.y & 1) * 128 + wn * 64 + ni * 16 + l16;
        float bb = bias[nloc];
        size_t hbase = (size_t)(nloc >> 4) * 3200 + (nloc & 15);
#pragma unroll
        for (int mi = 0; mi < 4; mi++) {
            int rowb = m0 + wm * 64 + mi * 16 + quad * 4;
#pragma unroll
            for (int r = 0; r < 4; r++) {
                unsigned row = rowb + r;
                unsigned bb_ = row / 200u, ll = row - bb_ * 200u;
                dst[(size_t)bb_ * 51200 + hbase + ll * 16] = f2bf(acc[mi][ni][r] + bb);
            }
        }
    }
}

// ---------------------------------------------------------------------------
// MHA per (b,h). grid 4096, block 256 (4 waves).
// S^T = K·Q^T: P lands in PV's A-operand layout in-register.
// r8: kf[13]/bv[13] hoisted out of the tile loop (t-invariant); softmax in
// exp2 domain (0.25*log2e folded into the S-FMA, v_exp_f32 = 2^x native);
// exp->pack->PV fused per kt (pf transient). RNE packs.
// ---------------------------------------------------------------------------
__global__ __launch_bounds__(256) void attn_k(
    u16* __restrict__ Q, const u16* __restrict__ K,
    const u16* __restrict__ V, const int* __restrict__ msk)
{
    const int blk = blockIdx.x;            // b*16+h
    const int b = blk >> 4;
    const int tid = threadIdx.x;
    const int wave = tid >> 6, lane = tid & 63;
    const int quad = lane >> 4, l16 = lane & 15;
    const size_t sbase = (size_t)blk * 3200;

    const float SL2E = 0.36067376022224085f;   // 0.25 * log2(e)
    const float AML2 = -14426.950408889634f;   // -10000 * log2(e)

    __shared__ u16 vt_s[16][228];              // V^T [dh][k], pitch 228
    __shared__ __align__(16) float am_s[224];  // additive key mask, exp2 domain

    for (int i = tid; i < 224; i += 256)
        am_s[i] = (i < 200) ? (msk[b * 200 + i] ? 0.f : AML2) : -1e30f;
    for (int i = tid; i < 16 * 28; i += 256)   // zero V^T pad cols 200..227
        vt_s[i / 28][200 + i % 28] = 0;
    for (int i = tid; i < 400; i += 256) {     // stage V^T
        int l = i >> 1, hf = i & 1;
        bfrag v = *(const bfrag*)(V + sbase + l * 16 + hf * 8);
#pragma unroll
        for (int j = 0; j < 8; j++) vt_s[hf * 8 + j][l] = (u16)v[j];
    }
    __syncthreads();

    // hoisted per-lane K fragment bases (row = l16, col = quad*4)
    const u16* Kb  = K + sbase + l16 * 16 + quad * 4;
    const u16* Kb8 = Kb + 8 * 256;
    const u16* K12 = (l16 > 7) ? (K + sbase + 199 * 16 + quad * 4)
                               : (Kb + 12 * 256);

    // t-invariant fragments: K (global, L1/L2-hit) and V^T (LDS)
    sfrag kf[13];
    sfrag bv[13];
#pragma unroll
    for (int kt = 0; kt < 13; kt++) {
        const u16* kp = (kt < 8) ? (Kb + kt * 256)
                      : (kt < 12) ? (Kb8 + (kt - 8) * 256) : K12;
        kf[kt] = *(const sfrag*)kp;
        bv[kt] = *(const sfrag*)&vt_s[l16][kt * 16 + quad * 4];
    }

    for (int t = wave; t < 13; t += 4) {
        int lq = t * 16 + l16; if (lq > 199) lq = 199;  // clamp (writes guarded)
        sfrag qf = *(const sfrag*)(Q + sbase + lq * 16 + quad * 4);

        // ---- S^T tiles (exp2 domain): s = c*0.25*log2e + am2
        float s[13][4];
#pragma unroll
        for (int kt = 0; kt < 13; kt++) {
            ffrag c = {0.f, 0.f, 0.f, 0.f};
            c = mfma16k16(kf[kt], qf, c);
            ffrag am4 = *(const ffrag*)&am_s[kt * 16 + quad * 4];
#pragma unroll
            for (int r = 0; r < 4; r++) s[kt][r] = __builtin_fmaf(c[r], SL2E, am4[r]);
        }
        // ---- max: per-lane 52, then cross-quad (xor 16,32)
        float mx = s[0][0];
#pragma unroll
        for (int kt = 0; kt < 13; kt++)
#pragma unroll
            for (int r = 0; r < 4; r++) mx = fmaxf(mx, s[kt][r]);
        mx = fmaxf(mx, __shfl_xor(mx, 16, 64));
        mx = fmaxf(mx, __shfl_xor(mx, 32, 64));
        // ---- fused exp2 + sum + pack + PV (P unnormalized)
        float sm = 0.f;
        ffrag o = {0.f, 0.f, 0.f, 0.f};
#pragma unroll
        for (int kt = 0; kt < 13; kt++) {
            float p0 = __builtin_amdgcn_exp2f(s[kt][0] - mx);
            float p1 = __builtin_amdgcn_exp2f(s[kt][1] - mx);
            float p2 = __builtin_amdgcn_exp2f(s[kt][2] - mx);
            float p3 = __builtin_amdgcn_exp2f(s[kt][3] - mx);
            sm += (p0 + p1) + (p2 + p3);
            union { sfrag v; u32 u[2]; } pk;
            pk.u[0] = pack2bf(p0, p1);
            pk.u[1] = pack2bf(p2, p3);
            o = mfma16k16(pk.v, bv[kt], o);
        }
        sm += __shfl_xor(sm, 16, 64);
        sm += __shfl_xor(sm, 32, 64);
        float rs = 1.0f / sm;
        // D row=quad*4+r = q-local, col=l16 = dh; normalize at write
        int lb = t * 16 + quad * 4;
        u16* qo = Q + sbase + lb * 16 + l16;
#pragma unroll
        for (int r = 0; r < 4; r++) {
            if (lb + r < 200)
                qo[r * 16] = f2bf(o[r] * rs);      // ctx in-place
        }
    }
}

// ---------------------------------------------------------------------------
// Query pooling per batch. grid 256, block 256. f32 out.
// ---------------------------------------------------------------------------
__global__ __launch_bounds__(256) void pool_k(
    const u16* __restrict__ NO, const int* __restrict__ msk,
    const float* __restrict__ qn, float* __restrict__ out)
{
    const int b = blockIdx.x;
    const int tid = threadIdx.x;
    __shared__ float q_sh[256];
    __shared__ float p_sh[256];
    __shared__ float redm[4], reds[4];

    q_sh[tid] = qn[tid];
    __syncthreads();

    float s = -1e30f;
    if (tid < 200) {
        const u16* row = NO + (size_t)(b * 200 + tid) * 256;
        float acc = 0.f;
        for (int d0 = 0; d0 < 256; d0 += 8) {
            bfrag v = *(const bfrag*)(row + d0);
#pragma unroll
            for (int j = 0; j < 8; j++) acc += bf2f((u16)v[j]) * q_sh[d0 + j];
        }
        s = acc * 0.0625f;
        if (msk[b * 200 + tid] == 0) s = -1e9f;
    }
    float m = s;
#pragma unroll
    for (int d = 1; d < 64; d <<= 1) m = fmaxf(m, __shfl_xor(m, d, 64));
    if ((tid & 63) == 0) redm[tid >> 6] = m;
    __syncthreads();
    m = fmaxf(fmaxf(redm[0], redm[1]), fmaxf(redm[2], redm[3]));
    float e = __expf(s - m);
    float sum = e;
#pragma unroll
    for (int d = 1; d < 64; d <<= 1) sum += __shfl_xor(sum, d, 64);
    if ((tid & 63) == 0) reds[tid >> 6] = sum;
    __syncthreads();
    sum = reds[0] + reds[1] + reds[2] + reds[3];
    p_sh[tid] = e / sum;
    __syncthreads();

    float acc = 0.f;
    for (int l = 0; l < 200; l++)
        acc += p_sh[l] * bf2f(NO[(size_t)(b * 200 + l) * 256 + tid]);
    out[(size_t)b * 256 + tid] = acc;
}

// ---------------------------------------------------------------------------
extern "C" void kernel_launch(void* const* d_in, const int* in_sizes, int n_in,
                              void* d_out, int out_size, void* d_ws, size_t ws_size,
                              hipStream_t stream) {
    const float* X   = (const float*)d_in[0];
    const int*   msk = (const int*)d_in[1];
    const float* Wq  = (const float*)d_in[2];
    const float* bq  = (const float*)d_in[3];
    const float* Wk  = (const float*)d_in[4];
    const float* bk  = (const float*)d_in[5];
    const float* Wv  = (const float*)d_in[6];
    const float* bv  = (const float*)d_in[7];
    const float* Wo  = (const float*)d_in[8];
    const float* bo  = (const float*)d_in[9];
    const float* qn  = (const float*)d_in[10];
    float* out = (float*)d_out;

    // ws layout:
    //   qbuf: Q head-major -> ctx in-place     26,214,400
    //   kbuf: K head-major -> news_out l-major 26,214,400
    //   vbuf: V head-major                     26,214,400
    //   wt:   [1024][256] bf16 weights^T          524,288
    //   Xb:   X cast to bf16 (big-ws path)     26,214,400  -> total 105,381,888
    char* ws = (char*)d_ws;
    u16* qbuf = (u16*)(ws);
    u16* kbuf = (u16*)(ws + 26214400);
    u16* vbuf = (u16*)(ws + 52428800);
    u16* wt   = (u16*)(ws + 78643200);
    u16* Xb   = (u16*)(ws + 79167488);
    const bool big = (ws_size >= 105381888ull);

    wtrans_k<<<dim3(4, 4, 4), 256, 0, stream>>>(Wq, Wk, Wv, Wo, wt);

    if (big) {
        xcast_k<<<1600, 256, 0, stream>>>(X, Xb);
        gemm8_k<true><<<dim3(400, 6), 256, 0, stream>>>(
            Xb, wt, bq, bk, bv, qbuf, kbuf, vbuf);
    } else {
        gemm_qkvf32_k<<<dim3(400, 6), 256, 0, stream>>>(
            X, wt, bq, bk, bv, qbuf, kbuf, vbuf);
    }

    attn_k<<<4096, 256, 0, stream>>>(qbuf, kbuf, vbuf, msk);

    gemm8_k<false><<<dim3(400, 2), 256, 0, stream>>>(
        qbuf, wt + 196608, bo, nullptr, nullptr, kbuf, nullptr, nullptr);

    pool_k<<<256, 256, 0, stream>>>(kbuf, msk, qn, out);
}

// Round 9
// 244.737 us; speedup vs baseline: 1.1331x; 1.1331x over previous
//
#include <hip/hip_runtime.h>

typedef unsigned short u16;
typedef unsigned int u32;
typedef unsigned long long u64;
typedef __attribute__((ext_vector_type(8))) short bfrag;  // 8 bf16 (4 VGPRs)
typedef __attribute__((ext_vector_type(4))) short sfrag;  // 4 bf16 (2 VGPRs)
typedef __attribute__((ext_vector_type(4))) float ffrag;  // 4 fp32

// B=256, L=200, D=256, H=16, Dh=16, M=51200
// Head-major slice: [B,H,L,16], slice stride 3200 u16, b-stride 51200 u16.

__device__ __forceinline__ float bf2f(u16 u) {
    union { float f; u32 i; } c; c.i = ((u32)u) << 16; return c.f;
}
__device__ __forceinline__ u16 f2bf(float f) {           // RNE
    union { float f; u32 i; } c; c.f = f;
    u32 r = c.i + 0x7FFFu + ((c.i >> 16) & 1u);
    return (u16)(r >> 16);
}
__device__ __forceinline__ u32 pack2bf(float lo, float hi) {  // RNE pair
    union { float f; u32 i; } a, b; a.f = lo; b.f = hi;
    u32 ra = a.i + 0x7FFFu + ((a.i >> 16) & 1u);
    u32 rb = b.i + 0x7FFFu + ((b.i >> 16) & 1u);
    return (ra >> 16) | (rb & 0xFFFF0000u);
}
__device__ __forceinline__ ffrag mfma16(bfrag a, bfrag b, ffrag c) {
    return __builtin_amdgcn_mfma_f32_16x16x32_bf16(a, b, c, 0, 0, 0);
}
__device__ __forceinline__ ffrag mfma16k16(sfrag a, sfrag b, ffrag c) {
    return __builtin_amdgcn_mfma_f32_16x16x16bf16_1k(a, b, c, 0, 0, 0);
}

// ---------------------------------------------------------------------------
// LDS-tiled transpose+cast: W[k][n] f32 -> Wt[n][k] bf16, 4 matrices.
// ---------------------------------------------------------------------------
__global__ __launch_bounds__(256) void wtrans_k(
    const float* __restrict__ W0, const float* __restrict__ W1,
    const float* __restrict__ W2, const float* __restrict__ W3,
    u16* __restrict__ Wt)
{
    __shared__ u16 t_s[64][72];
    const int mat = blockIdx.z;
    const float* W = (mat == 0) ? W0 : (mat == 1) ? W1 : (mat == 2) ? W2 : W3;
    const int k0 = blockIdx.x * 64, n0 = blockIdx.y * 64;
    const int r = threadIdx.x >> 2, cq = threadIdx.x & 3;

    const float* src = W + (size_t)(k0 + r) * 256 + n0 + cq * 16;
#pragma unroll
    for (int j = 0; j < 16; j += 4) {
        float4 f = *(const float4*)(src + j);
        t_s[cq * 16 + j + 0][r] = f2bf(f.x);
        t_s[cq * 16 + j + 1][r] = f2bf(f.y);
        t_s[cq * 16 + j + 2][r] = f2bf(f.z);
        t_s[cq * 16 + j + 3][r] = f2bf(f.w);
    }
    __syncthreads();
    u16* dst = Wt + ((size_t)mat * 256 + n0 + r) * 256 + k0 + cq * 16;
    *(bfrag*)(dst)     = *(const bfrag*)&t_s[r][cq * 16];
    *(bfrag*)(dst + 8) = *(const bfrag*)&t_s[r][cq * 16 + 8];
}

// ---------------------------------------------------------------------------
// GEMM (r7 structure — measured best): C = A @ Wt^T + bias.
// QKV=true : A = X (f32, l-major), grid (400,6), writes Q/K/V head-major bf16.
// QKV=false: A = ctx (bf16, head-major), grid (400,2), writes l-major bf16.
// block tile 128x128, wave tile 64x64, BK=32, XOR-swizzled LDS. RNE casts.
// ---------------------------------------------------------------------------
template<bool QKV>
__global__ __launch_bounds__(256) void gemm_k(
    const void* __restrict__ Avp, const u16* __restrict__ Wtp,
    const float* __restrict__ b0, const float* __restrict__ b1,
    const float* __restrict__ b2,
    u16* __restrict__ o0, u16* __restrict__ o1, u16* __restrict__ o2)
{
    const int m0 = blockIdx.x * 128;
    const int n0g = blockIdx.y * 128;
    const int tid = threadIdx.x;
    const int wave = tid >> 6, lane = tid & 63;
    const int quad = lane >> 4, l16 = lane & 15;
    const int wm = wave >> 1, wn = wave & 1;

    __shared__ __align__(16) u16 a_s[4][128][8];
    __shared__ __align__(16) u16 b_s[4][128][8];

    ffrag zf = {0.f, 0.f, 0.f, 0.f};
    ffrag acc[4][4];
#pragma unroll
    for (int mi = 0; mi < 4; mi++)
#pragma unroll
        for (int ni = 0; ni < 4; ni++) acc[mi][ni] = zf;

    const int sr = tid >> 2;
    const int sc = tid & 3;
    const float* Af = (const float*)Avp;
    const u16*   Ab = (const u16*)Avp;
    const u16* Wp = Wtp + (size_t)(n0g + sr) * 256 + sc * 8;

    int r0 = m0 + sr, r1 = r0 + 64;
    unsigned bA0 = (unsigned)r0 / 200u, bA1 = (unsigned)r1 / 200u;
    size_t base0 = (size_t)bA0 * 51200 + (r0 - bA0 * 200) * 16;
    size_t base1 = (size_t)bA1 * 51200 + (r1 - bA1 * 200) * 16;

    for (int kk = 0; kk < 256; kk += 32) {
        __syncthreads();
        if constexpr (QKV) {
            const float* p0 = Af + (size_t)r0 * 256 + sc * 8 + kk;
            const float* p1 = Af + (size_t)r1 * 256 + sc * 8 + kk;
            float4 f0 = *(const float4*)p0, f1 = *(const float4*)(p0 + 4);
            float4 g0 = *(const float4*)p1, g1 = *(const float4*)(p1 + 4);
            uint4 va = { pack2bf(f0.x, f0.y), pack2bf(f0.z, f0.w),
                         pack2bf(f1.x, f1.y), pack2bf(f1.z, f1.w) };
            uint4 vb = { pack2bf(g0.x, g0.y), pack2bf(g0.z, g0.w),
                         pack2bf(g1.x, g1.y), pack2bf(g1.z, g1.w) };
            *(uint4*)&a_s[sc][sr        ^ (sc << 2)][0] = va;
            *(uint4*)&a_s[sc][(sr + 64) ^ (sc << 2)][0] = vb;
        } else {
            int c = kk + sc * 8;
            size_t hofs = (size_t)(c >> 4) * 3200 + (c & 8);
            *(bfrag*)&a_s[sc][sr        ^ (sc << 2)][0] = *(const bfrag*)(Ab + base0 + hofs);
            *(bfrag*)&a_s[sc][(sr + 64) ^ (sc << 2)][0] = *(const bfrag*)(Ab + base1 + hofs);
        }
        *(bfrag*)&b_s[sc][sr        ^ (sc << 2)][0] = *(const bfrag*)(Wp + kk);
        *(bfrag*)&b_s[sc][(sr + 64) ^ (sc << 2)][0] = *(const bfrag*)(Wp + (size_t)64 * 256 + kk);
        __syncthreads();

        bfrag af[4], bfr[4];
#pragma unroll
        for (int mi = 0; mi < 4; mi++) {
            int m = wm * 64 + mi * 16 + l16;
            af[mi] = *(const bfrag*)&a_s[quad][m ^ (quad << 2)][0];
        }
#pragma unroll
        for (int ni = 0; ni < 4; ni++) {
            int n = wn * 64 + ni * 16 + l16;
            bfr[ni] = *(const bfrag*)&b_s[quad][n ^ (quad << 2)][0];
        }
#pragma unroll
        for (int mi = 0; mi < 4; mi++)
#pragma unroll
            for (int ni = 0; ni < 4; ni++)
                acc[mi][ni] = mfma16(af[mi], bfr[ni], acc[mi][ni]);
    }

    if constexpr (QKV) {
        const float* bias = (blockIdx.y < 2) ? b0 : (blockIdx.y < 4) ? b1 : b2;
        u16* dst = (blockIdx.y < 2) ? o0 : (blockIdx.y < 4) ? o1 : o2;
#pragma unroll
        for (int ni = 0; ni < 4; ni++) {
            int nloc = (blockIdx.y & 1) * 128 + wn * 64 + ni * 16 + l16;
            float bb = bias[nloc];
            size_t hbase = (size_t)(nloc >> 4) * 3200 + (nloc & 15);
#pragma unroll
            for (int mi = 0; mi < 4; mi++) {
                int rowb = m0 + wm * 64 + mi * 16 + quad * 4;
#pragma unroll
                for (int r = 0; r < 4; r++) {
                    unsigned row = rowb + r;
                    unsigned bb_ = row / 200u, ll = row - bb_ * 200u;
                    dst[(size_t)bb_ * 51200 + hbase + ll * 16] = f2bf(acc[mi][ni][r] + bb);
                }
            }
        }
    } else {
#pragma unroll
        for (int ni = 0; ni < 4; ni++) {
            int col = n0g + wn * 64 + ni * 16 + l16;
            float bb = b0[col];
#pragma unroll
            for (int mi = 0; mi < 4; mi++) {
                int rowb = m0 + wm * 64 + mi * 16 + quad * 4;
#pragma unroll
                for (int r = 0; r < 4; r++)
                    o0[(size_t)(rowb + r) * 256 + col] = f2bf(acc[mi][ni][r] + bb);
            }
        }
    }
}

// ---------------------------------------------------------------------------
// MHA per (b,h), KEY-COMPACTED. grid 4096, block 256 (4 waves).
// ~50% of keys are masked; reference gives them exp(-10000+s) == 0.0 exactly
// (f32 underflow), so excluding them is numerically EXACT. Ballot-compact the
// active key indices, gather K and V^T into LDS, loop nt=ceil(cnt/16) tiles
// (typ. 7) instead of 13. S^T = K_c·Q^T keeps P in PV's A-operand layout.
// Normalization applied BEFORE the P bf16 pack (r6 numeric recipe).
// All-masked row -> identity map (== reference's uniform softmax).
// ---------------------------------------------------------------------------
__global__ __launch_bounds__(256) void attn_k(
    u16* __restrict__ Q, const u16* __restrict__ K,
    const u16* __restrict__ V, const int* __restrict__ msk)
{
    const int blk = blockIdx.x;            // b*16+h
    const int b = blk >> 4;
    const int tid = threadIdx.x;
    const int wave = tid >> 6, lane = tid & 63;
    const int quad = lane >> 4, l16 = lane & 15;
    const size_t sbase = (size_t)blk * 3200;

    const float SL2E = 0.36067376022224085f;   // 0.25 * log2(e)

    __shared__ __align__(8)  u16 kc_s[208][20];   // compacted K rows (cols 0..15 used)
    __shared__ __align__(16) u16 vt_s[16][228];   // compacted V^T [dh][i]
    __shared__ __align__(16) float am_s[224];     // pad mask: 0 if i<cnt else -1e30
    __shared__ u16 idx_s[208];
    __shared__ int wcnt_s[4];

    // ---- ballot + zero-fill
    int m = 0;
    if (tid < 200) m = (msk[b * 200 + tid] != 0) ? 1 : 0;
    u64 bal = __ballot(m);
    if (lane == 0) wcnt_s[wave] = __popcll(bal);
    if (tid < 208) {
        u64* z = (u64*)&kc_s[tid][0];
        z[0] = 0; z[1] = 0; z[2] = 0; z[3] = 0;
    }
    u32* vz = (u32*)&vt_s[0][0];
    for (int i = tid; i < 1824; i += 256) vz[i] = 0;
    __syncthreads();

    int cnt = wcnt_s[0] + wcnt_s[1] + wcnt_s[2] + wcnt_s[3];
    if (cnt == 0) {                       // all masked -> uniform (== reference)
        if (tid < 200) idx_s[tid] = (u16)tid;
        cnt = 200;
    } else if (m) {
        int woff = (wave > 0 ? wcnt_s[0] : 0) + (wave > 1 ? wcnt_s[1] : 0)
                 + (wave > 2 ? wcnt_s[2] : 0);
        idx_s[woff + __popcll(bal & ((1ull << lane) - 1ull))] = (u16)tid;
    }
    for (int i = tid; i < 224; i += 256)
        am_s[i] = (i < cnt) ? 0.f : -1e30f;
    __syncthreads();

    // ---- gather compacted K rows and V^T columns
    if (tid < cnt) {
        int row = idx_s[tid];
        const u64* ks = (const u64*)(K + sbase + row * 16);
        u64* kd = (u64*)&kc_s[tid][0];
        kd[0] = ks[0]; kd[1] = ks[1]; kd[2] = ks[2]; kd[3] = ks[3];
        const u16* vp = V + sbase + row * 16;
        bfrag v0 = *(const bfrag*)vp;
        bfrag v1 = *(const bfrag*)(vp + 8);
#pragma unroll
        for (int j = 0; j < 8; j++) {
            vt_s[j][tid]     = (u16)v0[j];
            vt_s[8 + j][tid] = (u16)v1[j];
        }
    }
    __syncthreads();

    const int nt = (cnt + 15) >> 4;        // 1..13 active key tiles

    for (int t = wave; t < 13; t += 4) {
        int lq = t * 16 + l16; if (lq > 199) lq = 199;  // clamp (writes guarded)
        sfrag qf = *(const sfrag*)(Q + sbase + lq * 16 + quad * 4);

        // ---- S^T tiles over compacted keys (exp2 domain)
        float s[13][4];
#pragma unroll
        for (int kt = 0; kt < 13; kt++) {
            if (kt < nt) {
                sfrag kf = *(const sfrag*)&kc_s[kt * 16 + l16][quad * 4];
                ffrag c = {0.f, 0.f, 0.f, 0.f};
                c = mfma16k16(kf, qf, c);
                ffrag am4 = *(const ffrag*)&am_s[kt * 16 + quad * 4];
#pragma unroll
                for (int r = 0; r < 4; r++)
                    s[kt][r] = __builtin_fmaf(c[r], SL2E, am4[r]);
            }
        }
        // ---- max: per-lane, then cross-quad (xor 16,32 joins same-q lanes)
        float mx = -3e38f;
#pragma unroll
        for (int kt = 0; kt < 13; kt++)
            if (kt < nt)
#pragma unroll
                for (int r = 0; r < 4; r++) mx = fmaxf(mx, s[kt][r]);
        mx = fmaxf(mx, __shfl_xor(mx, 16, 64));
        mx = fmaxf(mx, __shfl_xor(mx, 32, 64));
        // ---- exp2 + sum (p stored back into s)
        float sm = 0.f;
#pragma unroll
        for (int kt = 0; kt < 13; kt++) {
            if (kt < nt) {
                float p0 = __builtin_amdgcn_exp2f(s[kt][0] - mx);
                float p1 = __builtin_amdgcn_exp2f(s[kt][1] - mx);
                float p2 = __builtin_amdgcn_exp2f(s[kt][2] - mx);
                float p3 = __builtin_amdgcn_exp2f(s[kt][3] - mx);
                sm += (p0 + p1) + (p2 + p3);
                s[kt][0] = p0; s[kt][1] = p1; s[kt][2] = p2; s[kt][3] = p3;
            }
        }
        sm += __shfl_xor(sm, 16, 64);
        sm += __shfl_xor(sm, 32, 64);
        float rs = 1.0f / sm;
        // ---- normalize -> pack -> PV (fused per tile)
        ffrag o = {0.f, 0.f, 0.f, 0.f};
#pragma unroll
        for (int kt = 0; kt < 13; kt++) {
            if (kt < nt) {
                union { sfrag v; u32 u[2]; } pk;
                pk.u[0] = pack2bf(s[kt][0] * rs, s[kt][1] * rs);
                pk.u[1] = pack2bf(s[kt][2] * rs, s[kt][3] * rs);
                sfrag bv = *(const sfrag*)&vt_s[l16][kt * 16 + quad * 4];
                o = mfma16k16(pk.v, bv, o);
            }
        }
        // D row=quad*4+r = q-local, col=l16 = dh
        int lb = t * 16 + quad * 4;
        u16* qo = Q + sbase + lb * 16 + l16;
#pragma unroll
        for (int r = 0; r < 4; r++) {
            if (lb + r < 200)
                qo[r * 16] = f2bf(o[r]);   // ctx in-place over Q
        }
    }
}

// ---------------------------------------------------------------------------
// Query pooling per batch. grid 256, block 512 (8 waves). f32 out.
// Both phases: wave-per-row, 8B coalesced loads (vs 2B serial loop before).
// ---------------------------------------------------------------------------
__global__ __launch_bounds__(512) void pool_k(
    const u16* __restrict__ NO, const int* __restrict__ msk,
    const float* __restrict__ qn, float* __restrict__ out)
{
    const int b = blockIdx.x;
    const int tid = threadIdx.x;
    const int wave = tid >> 6, lane = tid & 63;

    __shared__ float q_sh[256];
    __shared__ float s_sh[200];
    __shared__ float p_sh[200];
    __shared__ float red_s[16];          // [0..7] max, [8..15] sum
    __shared__ float part_s[8][256];

    if (tid < 256) q_sh[tid] = qn[tid];
    __syncthreads();

    const u16* base = NO + (size_t)b * 51200;

    // phase 1: s_l = dot(NO[l], q) / 16 — wave w owns rows 25w..25w+24
    for (int rr = 0; rr < 25; rr++) {
        int l = wave * 25 + rr;
        u64 v = *(const u64*)(base + l * 256 + lane * 4);
        float d = bf2f((u16)v)         * q_sh[lane * 4 + 0]
                + bf2f((u16)(v >> 16)) * q_sh[lane * 4 + 1]
                + bf2f((u16)(v >> 32)) * q_sh[lane * 4 + 2]
                + bf2f((u16)(v >> 48)) * q_sh[lane * 4 + 3];
#pragma unroll
        for (int dd = 1; dd < 64; dd <<= 1) d += __shfl_xor(d, dd, 64);
        if (lane == 0) s_sh[l] = d * 0.0625f;
    }
    __syncthreads();

    // softmax over 200 (masked -> -1e9, matches reference where())
    float s = -1e30f;
    if (tid < 200) s = msk[b * 200 + tid] ? s_sh[tid] : -1e9f;
    float mw = s;
#pragma unroll
    for (int dd = 1; dd < 64; dd <<= 1) mw = fmaxf(mw, __shfl_xor(mw, dd, 64));
    if (lane == 0) red_s[wave] = mw;
    __syncthreads();
    float mmax = red_s[0];
#pragma unroll
    for (int w = 1; w < 8; w++) mmax = fmaxf(mmax, red_s[w]);
    float e = (tid < 200) ? __expf(s - mmax) : 0.f;
    float sw = e;
#pragma unroll
    for (int dd = 1; dd < 64; dd <<= 1) sw += __shfl_xor(sw, dd, 64);
    if (lane == 0) red_s[8 + wave] = sw;
    __syncthreads();
    float ssum = 0.f;
#pragma unroll
    for (int w = 0; w < 8; w++) ssum += red_s[8 + w];
    if (tid < 200) p_sh[tid] = e / ssum;
    __syncthreads();

    // phase 2: out[d] = sum_l p_l * NO[l][d] — wave-per-25-rows, lane owns 4 d
    float a0 = 0.f, a1 = 0.f, a2 = 0.f, a3 = 0.f;
    for (int rr = 0; rr < 25; rr++) {
        int l = wave * 25 + rr;
        float p = p_sh[l];
        u64 v = *(const u64*)(base + l * 256 + lane * 4);
        a0 += p * bf2f((u16)v);
        a1 += p * bf2f((u16)(v >> 16));
        a2 += p * bf2f((u16)(v >> 32));
        a3 += p * bf2f((u16)(v >> 48));
    }
    part_s[wave][lane * 4 + 0] = a0;
    part_s[wave][lane * 4 + 1] = a1;
    part_s[wave][lane * 4 + 2] = a2;
    part_s[wave][lane * 4 + 3] = a3;
    __syncthreads();
    if (tid < 256) {
        float t = 0.f;
#pragma unroll
        for (int w = 0; w < 8; w++) t += part_s[w][tid];
        out[(size_t)b * 256 + tid] = t;
    }
}

// ---------------------------------------------------------------------------
extern "C" void kernel_launch(void* const* d_in, const int* in_sizes, int n_in,
                              void* d_out, int out_size, void* d_ws, size_t ws_size,
                              hipStream_t stream) {
    const float* X   = (const float*)d_in[0];
    const int*   msk = (const int*)d_in[1];
    const float* Wq  = (const float*)d_in[2];
    const float* bq  = (const float*)d_in[3];
    const float* Wk  = (const float*)d_in[4];
    const float* bk  = (const float*)d_in[5];
    const float* Wv  = (const float*)d_in[6];
    const float* bv  = (const float*)d_in[7];
    const float* Wo  = (const float*)d_in[8];
    const float* bo  = (const float*)d_in[9];
    const float* qn  = (const float*)d_in[10];
    float* out = (float*)d_out;

    // ws layout (79,167,488 B):
    //   qbuf: Q head-major -> ctx in-place     26,214,400
    //   kbuf: K head-major -> news_out l-major 26,214,400
    //   vbuf: V head-major                     26,214,400
    //   wt:   [1024][256] bf16 weights^T          524,288
    char* ws = (char*)d_ws;
    u16* qbuf = (u16*)(ws);
    u16* kbuf = (u16*)(ws + 26214400);
    u16* vbuf = (u16*)(ws + 52428800);
    u16* wt   = (u16*)(ws + 78643200);

    wtrans_k<<<dim3(4, 4, 4), 256, 0, stream>>>(Wq, Wk, Wv, Wo, wt);

    gemm_k<true><<<dim3(400, 6), 256, 0, stream>>>(
        X, wt, bq, bk, bv, qbuf, kbuf, vbuf);

    attn_k<<<4096, 256, 0, stream>>>(qbuf, kbuf, vbuf, msk);

    gemm_k<false><<<dim3(400, 2), 256, 0, stream>>>(
        qbuf, wt + 196608, bo, nullptr, nullptr, kbuf, nullptr, nullptr);

    pool_k<<<256, 512, 0, stream>>>(kbuf, msk, qn, out);
}